// Round 1
// 594.078 us; speedup vs baseline: 1.0121x; 1.0121x over previous
//
#include <hip/hip_runtime.h>
#include <math.h>

#define BATCH 2048
#define DIN   512
#define NS    256
#define NF    64
#define KG    768    // DIN+NS
#define NG    832    // gate cols: 256+64+256+256
#define NTOT  1088   // gate cols + 256 out-partial cols

__device__ __forceinline__ float sigmoidf_(float x) { return 1.0f / (1.0f + __expf(-x)); }

// ---------------- Kernel 1: fused gate GEMM + out-partial -------------------------
// C[2048,1088] = x_h @ [Wf|Wq|Wi|Wc|Wo_top]; BM=64 BN=64 BK=32, 256 thr, 4x4/thread,
// register-staged LDS double-buffer: ONE barrier per k-tile, prefetch overlaps FMA.
__global__ __launch_bounds__(256) void gates_gemm(
    const float* __restrict__ x, const float* __restrict__ h,
    const float* __restrict__ Wf, const float* __restrict__ bf,
    const float* __restrict__ Wq, const float* __restrict__ bq,
    const float* __restrict__ Wi, const float* __restrict__ bi,
    const float* __restrict__ Wc, const float* __restrict__ bcg,
    const float* __restrict__ Wo,
    float* __restrict__ gates, float* __restrict__ opart)
{
    __shared__ float As[2][32][68];   // [buf][k][m], row 272 B (16B aligned)
    __shared__ float Bs[2][32][68];   // [buf][k][n]

    const int nt = blockIdx.x;   // 0..16
    const int mt = blockIdx.y;   // 0..31
    const int t  = threadIdx.x;

    const int n0 = nt * 64;
    const float* Wp; const float* bp; int ld, noff, act;
    if (n0 < 256)      { Wp = Wf; bp = bf;  ld = 256; noff = 0;   act = 0; }
    else if (n0 < 320) { Wp = Wq; bp = bq;  ld = 64;  noff = 256; act = 0; }
    else if (n0 < 576) { Wp = Wi; bp = bi;  ld = 256; noff = 320; act = 0; }
    else if (n0 < 832) { Wp = Wc; bp = bcg; ld = 256; noff = 576; act = 1; }
    else               { Wp = Wo; bp = bf;  ld = 256; noff = 832; act = 2; }  // bp unused
    const int nloc0 = n0 - noff;

    const int tx = t & 15, ty = t >> 4;
    const int m0 = mt * 64;

    // A staging: lane = m row (conflict-free transposed LDS writes), wave picks k-chunk
    const int ar  = t & 63;
    const int ak0 = (t >> 6) * 8;      // 0,8,16,24
    // B staging: 8 lanes cover one 64-float row
    const int brow  = t >> 3;          // 0..31
    const int bcol0 = (t & 7) * 8;

    const float* ax = x + (size_t)(m0 + ar) * DIN;
    const float* ah = h + (size_t)(m0 + ar) * NS;

    float acc[4][4] = {};
    float4 a0, a1, b0, b1;

    // prologue: tile 0 -> buf 0
    {
        const int k0 = ak0;
        a0 = *(const float4*)(ax + k0);
        a1 = *(const float4*)(ax + k0 + 4);
        const float* wr = Wp + (size_t)brow * ld + nloc0 + bcol0;
        b0 = *(const float4*)wr; b1 = *(const float4*)(wr + 4);
        As[0][ak0 + 0][ar] = a0.x; As[0][ak0 + 1][ar] = a0.y;
        As[0][ak0 + 2][ar] = a0.z; As[0][ak0 + 3][ar] = a0.w;
        As[0][ak0 + 4][ar] = a1.x; As[0][ak0 + 5][ar] = a1.y;
        As[0][ak0 + 6][ar] = a1.z; As[0][ak0 + 7][ar] = a1.w;
        *(float4*)&Bs[0][brow][bcol0]     = b0;
        *(float4*)&Bs[0][brow][bcol0 + 4] = b1;
    }
    __syncthreads();

    #pragma unroll 1
    for (int tI = 0; tI < 24; ++tI) {
        const int notlast = (tI < 23);
        if (notlast) {                       // prefetch next tile into registers
            const int kt = (tI + 1) * 32;
            const int k0 = kt + ak0;
            a0 = (k0 < DIN)     ? *(const float4*)(ax + k0)
                                : *(const float4*)(ah + (k0 - DIN));
            a1 = (k0 + 4 < DIN) ? *(const float4*)(ax + k0 + 4)
                                : *(const float4*)(ah + (k0 + 4 - DIN));
            const float* wr = Wp + (size_t)(kt + brow) * ld + nloc0 + bcol0;
            b0 = *(const float4*)wr; b1 = *(const float4*)(wr + 4);
        }
        const float (*Asb)[68] = As[tI & 1];
        const float (*Bsb)[68] = Bs[tI & 1];
        #pragma unroll
        for (int kk = 0; kk < 32; ++kk) {
            const float4 a = *(const float4*)&Asb[kk][ty * 4];
            const float4 b = *(const float4*)&Bsb[kk][tx * 4];
            const float av[4] = { a.x, a.y, a.z, a.w };
            const float bv[4] = { b.x, b.y, b.z, b.w };
            #pragma unroll
            for (int r = 0; r < 4; ++r)
                #pragma unroll
                for (int c = 0; c < 4; ++c)
                    acc[r][c] = fmaf(av[r], bv[c], acc[r][c]);
        }
        if (notlast) {                       // write prefetched tile into other buffer
            float (*Ad)[68] = As[(tI + 1) & 1];
            float (*Bd)[68] = Bs[(tI + 1) & 1];
            Ad[ak0 + 0][ar] = a0.x; Ad[ak0 + 1][ar] = a0.y;
            Ad[ak0 + 2][ar] = a0.z; Ad[ak0 + 3][ar] = a0.w;
            Ad[ak0 + 4][ar] = a1.x; Ad[ak0 + 5][ar] = a1.y;
            Ad[ak0 + 6][ar] = a1.z; Ad[ak0 + 7][ar] = a1.w;
            *(float4*)&Bd[brow][bcol0]     = b0;
            *(float4*)&Bd[brow][bcol0 + 4] = b1;
        }
        __syncthreads();
    }

    if (act == 2) {
        // raw partial x_h @ Wo_top (bias added in kernel 3)
        #pragma unroll
        for (int r = 0; r < 4; ++r) {
            const int m = m0 + ty * 4 + r;
            *(float4*)(opart + (size_t)m * NS + (n0 - 832) + tx * 4) =
                make_float4(acc[r][0], acc[r][1], acc[r][2], acc[r][3]);
        }
    } else {
        const float4 bb = *(const float4*)(bp + nloc0 + tx * 4);
        const float bvv[4] = { bb.x, bb.y, bb.z, bb.w };
        #pragma unroll
        for (int r = 0; r < 4; ++r) {
            const int m = m0 + ty * 4 + r;
            float o[4];
            #pragma unroll
            for (int c = 0; c < 4; ++c) {
                float v = acc[r][c] + bvv[c];
                o[c] = act ? tanhf(v) : sigmoidf_(v);
            }
            *(float4*)(gates + (size_t)m * NG + n0 + tx * 4) =
                make_float4(o[0], o[1], o[2], o[3]);
        }
    }
}

// ---------------- Kernel 2: S update + A·u_a reduction -> c_t ---------------------
// one 16-lane group per (b,s); each lane handles 4 freqs via float4  (unchanged; at
// HBM roofline: 537 MB compulsory S traffic)
__global__ __launch_bounds__(256) void supdate(
    const float* __restrict__ S, const float* __restrict__ gates,
    const float* __restrict__ ua, const float* __restrict__ ba,
    const int* __restrict__ tptr,
    float* __restrict__ Sout, float* __restrict__ ct)
{
    const int tid = blockIdx.x * 256 + threadIdx.x;
    const int q    = tid & 15;
    const int pair = tid >> 4;
    const int b = pair >> 8, s = pair & 255;
    const int f0 = q * 4;
    const int tv = *tptr;

    const float* grow = gates + (size_t)b * NG;
    const float fste = grow[s];
    const float ic   = grow[320 + s] * grow[576 + s];

    const float4 ff  = *(const float4*)(grow + 256 + f0);
    const float4 ua4 = *(const float4*)(ua + f0);

    const size_t base0 = (((size_t)b * 2 + 0) * NS + s) * NF + f0;
    const size_t base1 = (((size_t)b * 2 + 1) * NS + s) * NF + f0;
    const float4 si0 = *(const float4*)(S + base0);
    const float4 si1 = *(const float4*)(S + base1);

    float fv[4] = { ff.x, ff.y, ff.z, ff.w };
    float uv[4] = { ua4.x, ua4.y, ua4.z, ua4.w };
    float a0[4] = { si0.x, si0.y, si0.z, si0.w };
    float a1[4] = { si1.x, si1.y, si1.z, si1.w };

    float part = 0.0f;
    float o0[4], o1[4];
    #pragma unroll
    for (int j = 0; j < 4; ++j) {
        int f = f0 + j;
        float ang = (float)((f * tv) & (NF - 1)) * (float)(M_PI / 32.0);
        float sn = __sinf(ang), cs = __cosf(ang);
        float F = fste * fv[j];
        float u = a0[j] * F + ic * sn;
        float v = a1[j] * F + ic * cs;
        o0[j] = u; o1[j] = v;
        part += sqrtf(u * u + v * v) * uv[j];
    }
    *(float4*)(Sout + base0) = make_float4(o0[0], o0[1], o0[2], o0[3]);
    *(float4*)(Sout + base1) = make_float4(o1[0], o1[1], o1[2], o1[3]);

    part += __shfl_xor(part, 1);
    part += __shfl_xor(part, 2);
    part += __shfl_xor(part, 4);
    part += __shfl_xor(part, 8);
    if (q == 0) ct[pair] = sigmoidf_(part + ba[s]);
}

// ---------------- Kernel 3: h = sigmoid(opart + c_t @ Wo_bot + b_o) * c_t ---------
// K=256 only. BM=32 BN=64 -> grid (4,64)=256 blocks (full GPU), 2x4/thread,
// same single-barrier double-buffered pipeline.
__global__ __launch_bounds__(256) void out_gemm(
    const float* __restrict__ ct, const float* __restrict__ opart,
    const float* __restrict__ Wo, const float* __restrict__ bo,
    float* __restrict__ hout)
{
    __shared__ float As[2][32][36];   // [buf][k][m(32)]
    __shared__ float Bs[2][32][68];   // [buf][k][n]

    const int t  = threadIdx.x;
    const int n0 = blockIdx.x * 64;   // 0..3
    const int m0 = blockIdx.y * 32;   // 0..63
    const int tx = t & 15, ty = t >> 4;

    const int ar  = t & 31;           // m row
    const int ak0 = (t >> 5) * 4;     // 0..28
    const int brow  = t >> 3;         // 0..31
    const int bcol0 = (t & 7) * 8;

    const float* Wp = Wo + (size_t)(DIN + NS) * NS;       // rows 768..1023
    const float* act_row = ct + (size_t)(m0 + ar) * NS;

    float acc[2][4] = {};
    float4 a4, b0, b1;

    // prologue: tile 0 -> buf 0
    a4 = *(const float4*)(act_row + ak0);
    {
        const float* wr = Wp + (size_t)brow * NS + n0 + bcol0;
        b0 = *(const float4*)wr; b1 = *(const float4*)(wr + 4);
    }
    As[0][ak0 + 0][ar] = a4.x; As[0][ak0 + 1][ar] = a4.y;
    As[0][ak0 + 2][ar] = a4.z; As[0][ak0 + 3][ar] = a4.w;
    *(float4*)&Bs[0][brow][bcol0]     = b0;
    *(float4*)&Bs[0][brow][bcol0 + 4] = b1;
    __syncthreads();

    #pragma unroll 1
    for (int tI = 0; tI < 8; ++tI) {
        const int notlast = (tI < 7);
        if (notlast) {
            const int kt = (tI + 1) * 32;
            a4 = *(const float4*)(act_row + kt + ak0);
            const float* wr = Wp + (size_t)(kt + brow) * NS + n0 + bcol0;
            b0 = *(const float4*)wr; b1 = *(const float4*)(wr + 4);
        }
        const float (*Asb)[36] = As[tI & 1];
        const float (*Bsb)[68] = Bs[tI & 1];
        #pragma unroll
        for (int kk = 0; kk < 32; ++kk) {
            const float a0v = Asb[kk][ty * 2];
            const float a1v = Asb[kk][ty * 2 + 1];
            const float4 b = *(const float4*)&Bsb[kk][tx * 4];
            acc[0][0] = fmaf(a0v, b.x, acc[0][0]);
            acc[0][1] = fmaf(a0v, b.y, acc[0][1]);
            acc[0][2] = fmaf(a0v, b.z, acc[0][2]);
            acc[0][3] = fmaf(a0v, b.w, acc[0][3]);
            acc[1][0] = fmaf(a1v, b.x, acc[1][0]);
            acc[1][1] = fmaf(a1v, b.y, acc[1][1]);
            acc[1][2] = fmaf(a1v, b.z, acc[1][2]);
            acc[1][3] = fmaf(a1v, b.w, acc[1][3]);
        }
        if (notlast) {
            float (*Ad)[36] = As[(tI + 1) & 1];
            float (*Bd)[68] = Bs[(tI + 1) & 1];
            Ad[ak0 + 0][ar] = a4.x; Ad[ak0 + 1][ar] = a4.y;
            Ad[ak0 + 2][ar] = a4.z; Ad[ak0 + 3][ar] = a4.w;
            *(float4*)&Bd[brow][bcol0]     = b0;
            *(float4*)&Bd[brow][bcol0 + 4] = b1;
        }
        __syncthreads();
    }

    #pragma unroll
    for (int r = 0; r < 2; ++r) {
        const int m = m0 + ty * 2 + r;
        const float4 op = *(const float4*)(opart + (size_t)m * NS + n0 + tx * 4);
        const float4 bb = *(const float4*)(bo + n0 + tx * 4);
        const float4 cv = *(const float4*)(ct + (size_t)m * NS + n0 + tx * 4);
        float4 o;
        o.x = sigmoidf_(acc[r][0] + op.x + bb.x) * cv.x;
        o.y = sigmoidf_(acc[r][1] + op.y + bb.y) * cv.y;
        o.z = sigmoidf_(acc[r][2] + op.z + bb.z) * cv.z;
        o.w = sigmoidf_(acc[r][3] + op.w + bb.w) * cv.w;
        *(float4*)(hout + (size_t)m * NS + n0 + tx * 4) = o;
    }
}

extern "C" void kernel_launch(void* const* d_in, const int* in_sizes, int n_in,
                              void* d_out, int out_size, void* d_ws, size_t ws_size,
                              hipStream_t stream)
{
    const float* x  = (const float*)d_in[0];
    const float* h  = (const float*)d_in[1];
    const float* S  = (const float*)d_in[2];
    const float* Wf = (const float*)d_in[3];
    const float* bf = (const float*)d_in[4];
    const float* Wq = (const float*)d_in[5];
    const float* bq = (const float*)d_in[6];
    const float* Wi = (const float*)d_in[7];
    const float* bi = (const float*)d_in[8];
    const float* Wc = (const float*)d_in[9];
    const float* bc = (const float*)d_in[10];
    const float* ua = (const float*)d_in[11];
    const float* ba = (const float*)d_in[12];
    const float* Wo = (const float*)d_in[13];
    const float* bo = (const float*)d_in[14];
    const int*   tp = (const int*)d_in[15];

    float* gates = (float*)d_ws;                       // [B, 832]
    float* ct    = gates + (size_t)BATCH * NG;         // [B, 256]
    float* opart = ct + (size_t)BATCH * NS;            // [B, 256] x_h @ Wo_top
    float* hout  = (float*)d_out;                      // [B, 256]
    float* Sout  = hout + (size_t)BATCH * NS;          // [B, 2, 256, 64]

    gates_gemm<<<dim3(17, 32), 256, 0, stream>>>(x, h, Wf, bf, Wq, bq, Wi, bi, Wc, bc, Wo, gates, opart);
    supdate<<<dim3((BATCH * NS * 16) / 256), 256, 0, stream>>>(S, gates, ua, ba, tp, Sout, ct);
    out_gemm<<<dim3(4, 64), 256, 0, stream>>>(ct, opart, Wo, bo, hout);
}

// Round 2
// 588.094 us; speedup vs baseline: 1.0224x; 1.0102x over previous
//
#include <hip/hip_runtime.h>
#include <math.h>

#define BATCH 2048
#define DIN   512
#define NS    256
#define NF    64
#define KG    768    // DIN+NS
#define NG    832    // gate cols: 256+64+256+256
#define NTOT  1088   // gate cols + 256 out-partial cols

typedef float v4f __attribute__((ext_vector_type(4)));

__device__ __forceinline__ float sigmoidf_(float x) { return 1.0f / (1.0f + __expf(-x)); }

// ---------------- Kernel 1: fused gate GEMM + out-partial -------------------------
// C[2048,1088] = x_h @ [Wf|Wq|Wi|Wc|Wo_top].
// BM=64 BN=32 BK=32, 128 threads, 4x4/thread, register-staged LDS double-buffer
// (one barrier per k-tile). Grid (34,32)=1088 blocks -> 4.25 blocks/CU (imbalance
// 1.18x vs 1.41x at 544 blocks) and ~6 resident blocks/CU for barrier overlap.
__global__ __launch_bounds__(128) void gates_gemm(
    const float* __restrict__ x, const float* __restrict__ h,
    const float* __restrict__ Wf, const float* __restrict__ bf,
    const float* __restrict__ Wq, const float* __restrict__ bq,
    const float* __restrict__ Wi, const float* __restrict__ bi,
    const float* __restrict__ Wc, const float* __restrict__ bcg,
    const float* __restrict__ Wo,
    float* __restrict__ gates, float* __restrict__ opart)
{
    __shared__ float As[2][32][68];   // [buf][k][m], row 272 B (16B aligned)
    __shared__ float Bs[2][32][36];   // [buf][k][n], row 144 B (16B aligned)

    const int nt = blockIdx.x;   // 0..33
    const int mt = blockIdx.y;   // 0..31
    const int t  = threadIdx.x;  // 0..127

    const int n0 = nt * 32;
    const float* Wp; const float* bp; int ld, noff, act;
    if (n0 < 256)      { Wp = Wf; bp = bf;  ld = 256; noff = 0;   act = 0; }
    else if (n0 < 320) { Wp = Wq; bp = bq;  ld = 64;  noff = 256; act = 0; }
    else if (n0 < 576) { Wp = Wi; bp = bi;  ld = 256; noff = 320; act = 0; }
    else if (n0 < 832) { Wp = Wc; bp = bcg; ld = 256; noff = 576; act = 1; }
    else               { Wp = Wo; bp = bf;  ld = 256; noff = 832; act = 2; }  // bp unused
    const int nloc0 = n0 - noff;

    const int tx = t & 7, ty = t >> 3;     // 8 x 16 thread grid -> 32n x 64m
    const int m0 = mt * 64;

    // A staging: lane = m row, wave picks 16-wide k-chunk (chunks never straddle DIN)
    const int ar  = t & 63;
    const int ak0 = (t >> 6) * 16;     // 0 or 16
    // B staging: 4 lanes cover one 32-float row (two 64B-contiguous quads)
    const int brow  = t >> 2;          // 0..31
    const int bcol0 = (t & 3) * 4;     // 0,4,8,12  (+16 for second quad)

    const float* ax = x + (size_t)(m0 + ar) * DIN;
    const float* ah = h + (size_t)(m0 + ar) * NS;

    float acc[4][4] = {};
    float4 a0, a1, a2, a3, b0, b1;

    // prologue: tile 0 -> buf 0   (k in [0,32): x only)
    {
        a0 = *(const float4*)(ax + ak0);
        a1 = *(const float4*)(ax + ak0 + 4);
        a2 = *(const float4*)(ax + ak0 + 8);
        a3 = *(const float4*)(ax + ak0 + 12);
        const float* wr = Wp + (size_t)brow * ld + nloc0 + bcol0;
        b0 = *(const float4*)wr; b1 = *(const float4*)(wr + 16);
        As[0][ak0 +  0][ar] = a0.x; As[0][ak0 +  1][ar] = a0.y;
        As[0][ak0 +  2][ar] = a0.z; As[0][ak0 +  3][ar] = a0.w;
        As[0][ak0 +  4][ar] = a1.x; As[0][ak0 +  5][ar] = a1.y;
        As[0][ak0 +  6][ar] = a1.z; As[0][ak0 +  7][ar] = a1.w;
        As[0][ak0 +  8][ar] = a2.x; As[0][ak0 +  9][ar] = a2.y;
        As[0][ak0 + 10][ar] = a2.z; As[0][ak0 + 11][ar] = a2.w;
        As[0][ak0 + 12][ar] = a3.x; As[0][ak0 + 13][ar] = a3.y;
        As[0][ak0 + 14][ar] = a3.z; As[0][ak0 + 15][ar] = a3.w;
        *(float4*)&Bs[0][brow][bcol0]      = b0;
        *(float4*)&Bs[0][brow][bcol0 + 16] = b1;
    }
    __syncthreads();

    #pragma unroll 1
    for (int tI = 0; tI < 24; ++tI) {
        const int notlast = (tI < 23);
        if (notlast) {                       // prefetch next tile into registers
            const int kt = (tI + 1) * 32;
            const int k0 = kt + ak0;
            const float* ap = (k0 < DIN) ? (ax + k0) : (ah + (k0 - DIN));
            a0 = *(const float4*)(ap);
            a1 = *(const float4*)(ap + 4);
            a2 = *(const float4*)(ap + 8);
            a3 = *(const float4*)(ap + 12);
            const float* wr = Wp + (size_t)(kt + brow) * ld + nloc0 + bcol0;
            b0 = *(const float4*)wr; b1 = *(const float4*)(wr + 16);
        }
        const float (*Asb)[68] = As[tI & 1];
        const float (*Bsb)[36] = Bs[tI & 1];
        #pragma unroll
        for (int kk = 0; kk < 32; ++kk) {
            const float4 a = *(const float4*)&Asb[kk][ty * 4];
            const float4 b = *(const float4*)&Bsb[kk][tx * 4];
            const float av[4] = { a.x, a.y, a.z, a.w };
            const float bv[4] = { b.x, b.y, b.z, b.w };
            #pragma unroll
            for (int r = 0; r < 4; ++r)
                #pragma unroll
                for (int c = 0; c < 4; ++c)
                    acc[r][c] = fmaf(av[r], bv[c], acc[r][c]);
        }
        if (notlast) {                       // write prefetched tile into other buffer
            float (*Ad)[68] = As[(tI + 1) & 1];
            float (*Bd)[36] = Bs[(tI + 1) & 1];
            Ad[ak0 +  0][ar] = a0.x; Ad[ak0 +  1][ar] = a0.y;
            Ad[ak0 +  2][ar] = a0.z; Ad[ak0 +  3][ar] = a0.w;
            Ad[ak0 +  4][ar] = a1.x; Ad[ak0 +  5][ar] = a1.y;
            Ad[ak0 +  6][ar] = a1.z; Ad[ak0 +  7][ar] = a1.w;
            Ad[ak0 +  8][ar] = a2.x; Ad[ak0 +  9][ar] = a2.y;
            Ad[ak0 + 10][ar] = a2.z; Ad[ak0 + 11][ar] = a2.w;
            Ad[ak0 + 12][ar] = a3.x; Ad[ak0 + 13][ar] = a3.y;
            Ad[ak0 + 14][ar] = a3.z; Ad[ak0 + 15][ar] = a3.w;
            *(float4*)&Bd[brow][bcol0]      = b0;
            *(float4*)&Bd[brow][bcol0 + 16] = b1;
        }
        __syncthreads();
    }

    if (act == 2) {
        // raw partial x_h @ Wo_top (bias added in kernel 3)
        #pragma unroll
        for (int r = 0; r < 4; ++r) {
            const int m = m0 + ty * 4 + r;
            *(float4*)(opart + (size_t)m * NS + (n0 - 832) + tx * 4) =
                make_float4(acc[r][0], acc[r][1], acc[r][2], acc[r][3]);
        }
    } else {
        const float4 bb = *(const float4*)(bp + nloc0 + tx * 4);
        const float bvv[4] = { bb.x, bb.y, bb.z, bb.w };
        #pragma unroll
        for (int r = 0; r < 4; ++r) {
            const int m = m0 + ty * 4 + r;
            float o[4];
            #pragma unroll
            for (int c = 0; c < 4; ++c) {
                float v = acc[r][c] + bvv[c];
                o[c] = act ? tanhf(v) : sigmoidf_(v);
            }
            *(float4*)(gates + (size_t)m * NG + n0 + tx * 4) =
                make_float4(o[0], o[1], o[2], o[3]);
        }
    }
}

// ---------------- Kernel 2: S update + A·u_a reduction -> c_t ---------------------
// one 16-lane group per (b,s); each lane handles 4 freqs via float4.
// At HBM roofline (537 MB compulsory S traffic); S/Sout streamed non-temporally
// (read-once/write-once -> don't thrash L2/L3).
__global__ __launch_bounds__(256) void supdate(
    const float* __restrict__ S, const float* __restrict__ gates,
    const float* __restrict__ ua, const float* __restrict__ ba,
    const int* __restrict__ tptr,
    float* __restrict__ Sout, float* __restrict__ ct)
{
    const int tid = blockIdx.x * 256 + threadIdx.x;
    const int q    = tid & 15;
    const int pair = tid >> 4;
    const int b = pair >> 8, s = pair & 255;
    const int f0 = q * 4;
    const int tv = *tptr;

    const float* grow = gates + (size_t)b * NG;
    const float fste = grow[s];
    const float ic   = grow[320 + s] * grow[576 + s];

    const float4 ff  = *(const float4*)(grow + 256 + f0);
    const float4 ua4 = *(const float4*)(ua + f0);

    const size_t base0 = (((size_t)b * 2 + 0) * NS + s) * NF + f0;
    const size_t base1 = (((size_t)b * 2 + 1) * NS + s) * NF + f0;
    const v4f si0 = __builtin_nontemporal_load((const v4f*)(S + base0));
    const v4f si1 = __builtin_nontemporal_load((const v4f*)(S + base1));

    float fv[4] = { ff.x, ff.y, ff.z, ff.w };
    float uv[4] = { ua4.x, ua4.y, ua4.z, ua4.w };
    float a0[4] = { si0.x, si0.y, si0.z, si0.w };
    float a1[4] = { si1.x, si1.y, si1.z, si1.w };

    float part = 0.0f;
    v4f o0, o1;
    #pragma unroll
    for (int j = 0; j < 4; ++j) {
        int f = f0 + j;
        float ang = (float)((f * tv) & (NF - 1)) * (float)(M_PI / 32.0);
        float sn = __sinf(ang), cs = __cosf(ang);
        float F = fste * fv[j];
        float u = a0[j] * F + ic * sn;
        float v = a1[j] * F + ic * cs;
        o0[j] = u; o1[j] = v;
        part += sqrtf(u * u + v * v) * uv[j];
    }
    __builtin_nontemporal_store(o0, (v4f*)(Sout + base0));
    __builtin_nontemporal_store(o1, (v4f*)(Sout + base1));

    part += __shfl_xor(part, 1);
    part += __shfl_xor(part, 2);
    part += __shfl_xor(part, 4);
    part += __shfl_xor(part, 8);
    if (q == 0) ct[pair] = sigmoidf_(part + ba[s]);
}

// ---------------- Kernel 3: h = sigmoid(opart + c_t @ Wo_bot + b_o) * c_t ---------
// K=256 only. BM=32 BN=64 -> grid (4,64)=256 blocks (full GPU), 2x4/thread,
// single-barrier double-buffered pipeline.
__global__ __launch_bounds__(256) void out_gemm(
    const float* __restrict__ ct, const float* __restrict__ opart,
    const float* __restrict__ Wo, const float* __restrict__ bo,
    float* __restrict__ hout)
{
    __shared__ float As[2][32][36];   // [buf][k][m(32)]
    __shared__ float Bs[2][32][68];   // [buf][k][n]

    const int t  = threadIdx.x;
    const int n0 = blockIdx.x * 64;   // 0..3
    const int m0 = blockIdx.y * 32;   // 0..63
    const int tx = t & 15, ty = t >> 4;

    const int ar  = t & 31;           // m row
    const int ak0 = (t >> 5) * 4;     // 0..28
    const int brow  = t >> 3;         // 0..31
    const int bcol0 = (t & 7) * 8;

    const float* Wp = Wo + (size_t)(DIN + NS) * NS;       // rows 768..1023
    const float* act_row = ct + (size_t)(m0 + ar) * NS;

    float acc[2][4] = {};
    float4 a4, b0, b1;

    // prologue: tile 0 -> buf 0
    a4 = *(const float4*)(act_row + ak0);
    {
        const float* wr = Wp + (size_t)brow * NS + n0 + bcol0;
        b0 = *(const float4*)wr; b1 = *(const float4*)(wr + 4);
    }
    As[0][ak0 + 0][ar] = a4.x; As[0][ak0 + 1][ar] = a4.y;
    As[0][ak0 + 2][ar] = a4.z; As[0][ak0 + 3][ar] = a4.w;
    *(float4*)&Bs[0][brow][bcol0]     = b0;
    *(float4*)&Bs[0][brow][bcol0 + 4] = b1;
    __syncthreads();

    #pragma unroll 1
    for (int tI = 0; tI < 8; ++tI) {
        const int notlast = (tI < 7);
        if (notlast) {
            const int kt = (tI + 1) * 32;
            a4 = *(const float4*)(act_row + kt + ak0);
            const float* wr = Wp + (size_t)(kt + brow) * NS + n0 + bcol0;
            b0 = *(const float4*)wr; b1 = *(const float4*)(wr + 4);
        }
        const float (*Asb)[36] = As[tI & 1];
        const float (*Bsb)[68] = Bs[tI & 1];
        #pragma unroll
        for (int kk = 0; kk < 32; ++kk) {
            const float a0v = Asb[kk][ty * 2];
            const float a1v = Asb[kk][ty * 2 + 1];
            const float4 b = *(const float4*)&Bsb[kk][tx * 4];
            acc[0][0] = fmaf(a0v, b.x, acc[0][0]);
            acc[0][1] = fmaf(a0v, b.y, acc[0][1]);
            acc[0][2] = fmaf(a0v, b.z, acc[0][2]);
            acc[0][3] = fmaf(a0v, b.w, acc[0][3]);
            acc[1][0] = fmaf(a1v, b.x, acc[1][0]);
            acc[1][1] = fmaf(a1v, b.y, acc[1][1]);
            acc[1][2] = fmaf(a1v, b.z, acc[1][2]);
            acc[1][3] = fmaf(a1v, b.w, acc[1][3]);
        }
        if (notlast) {
            float (*Ad)[36] = As[(tI + 1) & 1];
            float (*Bd)[68] = Bs[(tI + 1) & 1];
            Ad[ak0 + 0][ar] = a4.x; Ad[ak0 + 1][ar] = a4.y;
            Ad[ak0 + 2][ar] = a4.z; Ad[ak0 + 3][ar] = a4.w;
            *(float4*)&Bd[brow][bcol0]     = b0;
            *(float4*)&Bd[brow][bcol0 + 4] = b1;
        }
        __syncthreads();
    }

    #pragma unroll
    for (int r = 0; r < 2; ++r) {
        const int m = m0 + ty * 2 + r;
        const float4 op = *(const float4*)(opart + (size_t)m * NS + n0 + tx * 4);
        const float4 bb = *(const float4*)(bo + n0 + tx * 4);
        const float4 cv = *(const float4*)(ct + (size_t)m * NS + n0 + tx * 4);
        float4 o;
        o.x = sigmoidf_(acc[r][0] + op.x + bb.x) * cv.x;
        o.y = sigmoidf_(acc[r][1] + op.y + bb.y) * cv.y;
        o.z = sigmoidf_(acc[r][2] + op.z + bb.z) * cv.z;
        o.w = sigmoidf_(acc[r][3] + op.w + bb.w) * cv.w;
        *(float4*)(hout + (size_t)m * NS + n0 + tx * 4) = o;
    }
}

extern "C" void kernel_launch(void* const* d_in, const int* in_sizes, int n_in,
                              void* d_out, int out_size, void* d_ws, size_t ws_size,
                              hipStream_t stream)
{
    const float* x  = (const float*)d_in[0];
    const float* h  = (const float*)d_in[1];
    const float* S  = (const float*)d_in[2];
    const float* Wf = (const float*)d_in[3];
    const float* bf = (const float*)d_in[4];
    const float* Wq = (const float*)d_in[5];
    const float* bq = (const float*)d_in[6];
    const float* Wi = (const float*)d_in[7];
    const float* bi = (const float*)d_in[8];
    const float* Wc = (const float*)d_in[9];
    const float* bc = (const float*)d_in[10];
    const float* ua = (const float*)d_in[11];
    const float* ba = (const float*)d_in[12];
    const float* Wo = (const float*)d_in[13];
    const float* bo = (const float*)d_in[14];
    const int*   tp = (const int*)d_in[15];

    float* gates = (float*)d_ws;                       // [B, 832]
    float* ct    = gates + (size_t)BATCH * NG;         // [B, 256]
    float* opart = ct + (size_t)BATCH * NS;            // [B, 256] x_h @ Wo_top
    float* hout  = (float*)d_out;                      // [B, 256]
    float* Sout  = hout + (size_t)BATCH * NS;          // [B, 2, 256, 64]

    gates_gemm<<<dim3(34, 32), 128, 0, stream>>>(x, h, Wf, bf, Wq, bq, Wi, bi, Wc, bc, Wo, gates, opart);
    supdate<<<dim3((BATCH * NS * 16) / 256), 256, 0, stream>>>(S, gates, ua, ba, tp, Sout, ct);
    out_gemm<<<dim3(4, 64), 256, 0, stream>>>(ct, opart, Wo, bo, hout);
}